// Round 12
// baseline (229.423 us; speedup 1.0000x reference)
//
#include <hip/hip_runtime.h>
#include <hip/hip_bf16.h>

typedef __hip_bfloat16 BF16;
typedef __attribute__((ext_vector_type(8))) short bf16x8;
typedef __attribute__((ext_vector_type(4))) short bf16x4;
typedef __attribute__((ext_vector_type(4))) float f32x4;
typedef __attribute__((ext_vector_type(4))) int int4v;
typedef __attribute__((ext_vector_type(2))) int int2v;

#define MTOK 12608      // 64*197 tokens
#define D_IN 768
#define KAUG 832        // 768 + 64 (E*R)
#define N_QKV 2304

#define AS1 __attribute__((address_space(1)))
#define AS3 __attribute__((address_space(3)))
#define SB0() __builtin_amdgcn_sched_barrier(0)

#if __has_builtin(__builtin_amdgcn_mfma_f32_16x16x16bf16_1k)
__device__ __forceinline__ f32x4 mfma16(bf16x4 a, bf16x4 b, f32x4 c) {
  return __builtin_amdgcn_mfma_f32_16x16x16bf16_1k(a, b, c, 0, 0, 0);
}
#else
__device__ __forceinline__ f32x4 mfma16(bf16x4 a, bf16x4 b, f32x4 c) {
  f32x4 d;
  asm volatile("v_mfma_f32_16x16x16_bf16 %0, %1, %2, %3"
               : "=v"(d) : "v"(a), "v"(b), "0"(c));
  return d;
}
#endif

// ---------------- prep kernels ----------------
__global__ __launch_bounds__(256) void prep_waug_k(const float* __restrict__ qkv_w,
                                                   const float* __restrict__ lora_b,
                                                   BF16* __restrict__ Waug) {
  int idx = blockIdx.x*256 + threadIdx.x;
  if (idx >= N_QKV*KAUG) return;
  int k = idx / KAUG, c = idx - k*KAUG;
  float v = (c < D_IN) ? qkv_w[k*D_IN + c] : lora_b[(size_t)(c - D_IN)*N_QKV + k];
  Waug[idx] = (BF16)v;
}

__global__ __launch_bounds__(256) void prep_pb_k(const float* __restrict__ proj_w,
                                                 BF16* __restrict__ Pb) {
  int idx = blockIdx.x*256 + threadIdx.x;
  if (idx < D_IN*D_IN) Pb[idx] = (BF16)proj_w[idx];
}

__global__ __launch_bounds__(256) void prep_lat_k(const float* __restrict__ lora_a,
                                                  BF16* __restrict__ LAt) {
  int idx = blockIdx.x*256 + threadIdx.x;
  if (idx >= 64*D_IN) return;
  int j = idx / D_IN, d = idx - j*D_IN;
  LAt[idx] = (BF16)lora_a[(size_t)(j >> 3)*6144 + d*8 + (j & 7)];
}

// ---------------- token prep: float4-vectorized cast + gate softmax -------
__global__ __launch_bounds__(256) void token_prep_k(const float* __restrict__ tokens,
                                                    const float* __restrict__ gate_w,
                                                    BF16* __restrict__ Aaug,
                                                    float* __restrict__ gates) {
  int w = blockIdx.x*4 + (threadIdx.x >> 6);
  int lane = threadIdx.x & 63;
  if (w >= MTOK) return;
  const float4* x4 = (const float4*)(tokens + (size_t)w*D_IN);
  float4 xv[3];
  #pragma unroll
  for (int i=0;i<3;++i) xv[i] = x4[lane + 64*i];
  #pragma unroll
  for (int i=0;i<3;++i) {
    ushort4 u;
    BF16 b0 = (BF16)xv[i].x, b1 = (BF16)xv[i].y, b2 = (BF16)xv[i].z, b3 = (BF16)xv[i].w;
    u.x = *(unsigned short*)&b0; u.y = *(unsigned short*)&b1;
    u.z = *(unsigned short*)&b2; u.w = *(unsigned short*)&b3;
    *(ushort4*)(Aaug + (size_t)w*KAUG + (lane + 64*i)*4) = u;
  }
  float g[8] = {0,0,0,0,0,0,0,0};
  #pragma unroll
  for (int i=0;i<3;++i) {
    const int d4 = (lane + 64*i)*4;
    #pragma unroll
    for (int e=0;e<8;++e) {
      float4 gw = *(const float4*)(gate_w + e*D_IN + d4);
      g[e] += xv[i].x*gw.x + xv[i].y*gw.y + xv[i].z*gw.z + xv[i].w*gw.w;
    }
  }
  #pragma unroll
  for (int e=0;e<8;++e) {
    #pragma unroll
    for (int off=32; off; off >>= 1) g[e] += __shfl_xor(g[e], off);
  }
  float mx = g[0];
  #pragma unroll
  for (int e=1;e<8;++e) mx = fmaxf(mx, g[e]);
  float pe[8]; float ssum = 0.f;
  #pragma unroll
  for (int e=0;e<8;++e) { pe[e] = __expf(g[e]-mx); ssum += pe[e]; }
  float inv = 1.f/ssum;
  if (lane < 8) {
    float val = 0.f;
    #pragma unroll
    for (int e=0;e<8;++e) val = (lane==e) ? pe[e]*inv : val;
    gates[(size_t)w*8 + lane] = val;
  }
}

// ---------------- small 2-phase GEMM-BT (h-GEMM only) ----------------
template<int ROWS>
__device__ __forceinline__ void stage_bt(const BF16* __restrict__ g, int ldg, int row0, int M,
                                         BF16* lds, int kbase, int t) {
  constexpr int NIT = ROWS*8/256;
  #pragma unroll
  for (int it=0; it<NIT; ++it) {
    int c = it*256 + t;
    int r = c >> 3, kc = c & 7;
    int rg = row0 + r;
    rg = (rg < M) ? rg : (M-1);
    const BF16* gp = g + (size_t)rg*ldg + kbase + kc*8;
    BF16* lp = lds + (it*256 + (t & ~63))*8;
    __builtin_amdgcn_global_load_lds((const AS1 void*)gp, (AS3 void*)lp, 16, 0, 0);
  }
}

template<int BM, int BN, int EPI>
__global__ __launch_bounds__(256,3) void gemm_bt_k(const BF16* __restrict__ A, int lda,
                                                   const BF16* __restrict__ Bt, int ldb,
                                                   const float* __restrict__ aux,
                                                   void* __restrict__ Cv, int ldc,
                                                   int M, int K) {
  constexpr int BK = 64;
  constexpr int WM = BM/2, WN = BN/2;
  constexpr int MF = WM/16, NF = WN/16;
  __shared__ BF16 Al[BM*BK];
  __shared__ BF16 Bl[BN*BK];
  const int n0 = blockIdx.x*BN, m0 = blockIdx.y*BM;
  const int t = threadIdx.x, lane = t & 63, wid = t >> 6;
  const int wm = (wid >> 1)*WM, wn = (wid & 1)*WN;
  f32x4 acc[MF][NF] = {};
  const int KT = K/BK;
  for (int kt=0; kt<KT; ++kt) {
    stage_bt<BM>(A, lda, m0, M, Al, kt*BK, t);
    stage_bt<BN>(Bt, ldb, n0, 1<<30, Bl, kt*BK, t);
    __syncthreads();
    #pragma unroll
    for (int kk=0; kk<2; ++kk) {
      bf16x8 a[MF], b[NF];
      const int col = kk*32 + (lane >> 4)*8;
      #pragma unroll
      for (int m=0;m<MF;++m) a[m] = *(const bf16x8*)(Al + (wm + m*16 + (lane & 15))*BK + col);
      #pragma unroll
      for (int n=0;n<NF;++n) b[n] = *(const bf16x8*)(Bl + (wn + n*16 + (lane & 15))*BK + col);
      #pragma unroll
      for (int m=0;m<MF;++m)
        #pragma unroll
        for (int n=0;n<NF;++n)
          acc[m][n] = __builtin_amdgcn_mfma_f32_16x16x32_bf16(a[m], b[n], acc[m][n], 0, 0, 0);
    }
    __syncthreads();
  }
  #pragma unroll
  for (int m=0;m<MF;++m) {
    #pragma unroll
    for (int n=0;n<NF;++n) {
      const int rb = m0 + wm + m*16 + (lane >> 4)*4;
      const int c = n0 + wn + n*16 + (lane & 15);
      #pragma unroll
      for (int j=0;j<4;++j) {
        const int r = rb + j;
        if (r < M) {
          float v = acc[m][n][j];
          if (EPI == 0) {
            v *= aux[(size_t)r*8 + (c >> 3)];
            ((BF16*)Cv)[(size_t)r*ldc + c] = (BF16)v;
          } else if (EPI == 1) {
            v += aux[c];
            ((BF16*)Cv)[(size_t)r*ldc + c] = (BF16)v;
          } else {
            v += aux[c];
            ((float*)Cv)[(size_t)r*ldc + c] = v;
          }
        }
      }
    }
  }
}

// ---------------- 128x128 GEMM-BT, A in LDS dbuf, B direct from L2 --------
// Round-11: B-fragments read straight from global (B is L2-hot: 3.8 MB QKV /
// 1.2 MB proj) -> LDS halves to 32 KiB -> 3 blocks/CU TLP; ds_read count
// halves (round-6 V3 showed LDS chain was the cost center). vmcnt ledger:
// issue B(t) x8 FIRST, stageA(t+1) x4 after -> vmcnt(4) drains B only.
template<int EPI, int NBN, int LDA, int LDB, int LDC>
__global__ __launch_bounds__(256,3) void gemm3_k(const BF16* __restrict__ A,
                                                 const BF16* __restrict__ Bt,
                                                 const float* __restrict__ bias,
                                                 void* __restrict__ Cv,
                                                 int M, int K) {
  __shared__ BF16 Ash[2][8192];             // [buf][128*64], G4-swizzled
  const int t = threadIdx.x, lane = t & 63, wid = t >> 6;
  const int nwg = gridDim.x;
  const int q8 = nwg >> 3, r8 = nwg & 7;
  const int xcd = blockIdx.x & 7, pos = blockIdx.x >> 3;
  const int wg = (xcd < r8 ? xcd*(q8+1) : r8*(q8+1) + (xcd - r8)*q8) + pos;
  const int mb = wg / NBN, nb = wg - mb*NBN;
  const int m0 = mb*128, n0 = nb*128;
  const int KT = K/64;
  const int q4 = lane & 15, g = lane >> 4;
  const int wm = (wid >> 1)*64, wn = (wid & 1)*64;

  // A stage sources (4 chunks/thread, inverse-swizzled within row)
  const BF16 *sA[4];
  #pragma unroll
  for (int it=0; it<4; ++it) {
    int c = it*256 + t;
    int r = c >> 3, p = c & 7;
    int sc = p ^ (r & 7);
    int ra = m0 + r; ra = ra < M ? ra : M-1;
    sA[it] = A + (size_t)ra*LDA + sc*8;
  }
  auto stageA = [&](int buf, int tile) {
    #pragma unroll
    for (int it=0; it<4; ++it)
      __builtin_amdgcn_global_load_lds((const AS1 void*)(sA[it] + tile*64),
        (AS3 void*)(&Ash[buf][0] + (it*256 + (t & ~63))*8), 16, 0, 0);
  };

  // B fragment sources: row n0+wn+n*16+q4 (always in-range), col kk*32+g*8
  const BF16* pB[4][2];
  #pragma unroll
  for (int n=0;n<4;++n)
    #pragma unroll
    for (int kk=0;kk<2;++kk)
      pB[n][kk] = Bt + (size_t)(n0 + wn + n*16 + q4)*LDB + kk*32 + g*8;

  // swizzled A read columns
  const int sw = (q4 & 7) << 3;
  const int ck[2] = { ((g*8)) ^ sw, ((32 + g*8)) ^ sw };

  f32x4 acc[4][4] = {};
  stageA(0, 0);
  asm volatile("s_waitcnt vmcnt(0)" ::: "memory"); SB0();
  __builtin_amdgcn_s_barrier();

  for (int kt = 0; kt < KT; ++kt) {
    const int buf = kt & 1;
    const bool nb1 = (kt+1 < KT);
    // B(t) global loads first (8 vm, oldest)
    bf16x8 bb[4][2];
    #pragma unroll
    for (int n=0;n<4;++n)
      #pragma unroll
      for (int kk=0;kk<2;++kk)
        bb[n][kk] = *(const bf16x8*)(pB[n][kk] + kt*64);
    SB0();
    // A(t+1) stage after (4 vm, newest)
    if (nb1) stageA(buf^1, kt+1);
    SB0();
    // A(t) fragments from LDS
    bf16x8 aa[4][2];
    #pragma unroll
    for (int m=0;m<4;++m)
      #pragma unroll
      for (int kk=0;kk<2;++kk)
        aa[m][kk] = *(const bf16x8*)(&Ash[buf][0] + (wm + m*16 + q4)*64 + ck[kk]);
    SB0();
    if (nb1) asm volatile("s_waitcnt vmcnt(4) lgkmcnt(0)" ::: "memory");
    else     asm volatile("s_waitcnt vmcnt(0) lgkmcnt(0)" ::: "memory");
    SB0();
    __builtin_amdgcn_s_setprio(1);
    #pragma unroll
    for (int kk=0;kk<2;++kk)
      #pragma unroll
      for (int m=0;m<4;++m)
        #pragma unroll
        for (int n=0;n<4;++n)
          acc[m][n] = __builtin_amdgcn_mfma_f32_16x16x32_bf16(aa[m][kk], bb[n][kk], acc[m][n], 0,0,0);
    __builtin_amdgcn_s_setprio(0);
    SB0();
    if (nb1) asm volatile("s_waitcnt vmcnt(0)" ::: "memory");  // A(t+1) landed
    SB0();
    __builtin_amdgcn_s_barrier();
  }

  float bv[4];
  #pragma unroll
  for (int n=0;n<4;++n) bv[n] = bias[n0 + wn + n*16 + q4];
  #pragma unroll
  for (int m=0;m<4;++m) {
    #pragma unroll
    for (int j=0;j<4;++j) {
      const int r = m0 + wm + m*16 + g*4 + j;
      if (r < M) {
        #pragma unroll
        for (int n=0;n<4;++n) {
          float v = acc[m][n][j] + bv[n];
          const size_t idx = (size_t)r*LDC + n0 + wn + n*16 + q4;
          if (EPI == 1) ((BF16*)Cv)[idx] = (BF16)v;
          else          ((float*)Cv)[idx] = v;
        }
      }
    }
  }
}

// ---------------- attention: swapped QK^T + direct-register PV ----------
__device__ __forceinline__ int pack2bf(float lo, float hi) {
  BF16 a = (BF16)lo, b = (BF16)hi;
  unsigned short al = *(unsigned short*)&a, bh = *(unsigned short*)&b;
  return (int)(((unsigned)bh << 16) | (unsigned)al);
}

__global__ __launch_bounds__(256,2) void attn_k(const BF16* __restrict__ QKV,
                                                BF16* __restrict__ O) {
  constexpr int KSTR = 72;   // 144B rows: 2-way bank alias (free)
  constexpr int VSTR = 236;  // 472B rows: 16 lanes cover all 32 banks
  constexpr int OSTR = 72;   // O-stage rows 144B, 16B-aligned, 2-way max
  __shared__ BF16 Kl[208*KSTR];
  __shared__ BF16 Vt[64*VSTR];
  __shared__ BF16 Ol[4][16*OSTR];
  const int bh = blockIdx.x;
  const int b = bh / 12, h = bh - b*12;
  const size_t rowbase = (size_t)b*197;
  const int t = threadIdx.x, lane = t & 63, wid = t >> 6;
  const BF16 z = (BF16)0.0f;
  // ---- prefetch-split staging: issue ALL global loads, then store ----
  int4v rk[7], rv[7];
  int cc[7];
  #pragma unroll
  for (int it=0; it<7; ++it) {
    int c = t + it*256; c = (c < 1663) ? c : 1663;
    cc[it] = c;
    int r = c >> 3, kc = c & 7;
    int rr = (r < 197) ? r : 196;
    rk[it] = *(const int4v*)(QKV + (rowbase + rr)*N_QKV + 768  + h*64 + kc*8);
    rv[it] = *(const int4v*)(QKV + (rowbase + rr)*N_QKV + 1536 + h*64 + kc*8);
  }
  #pragma unroll
  for (int it=0; it<7; ++it) {
    int c = cc[it];
    int r = c >> 3, kc = c & 7;
    int4v kval = rk[it];
    if (r >= 197) { kval[0]=0; kval[1]=0; kval[2]=0; kval[3]=0; }
    *(int4v*)(Kl + r*KSTR + kc*8) = kval;
    const BF16* pv = (const BF16*)&rv[it];
    if (r < 197) {
      #pragma unroll
      for (int i=0;i<8;++i) Vt[(kc*8 + i)*VSTR + r] = pv[i];
    } else {
      #pragma unroll
      for (int i=0;i<8;++i) Vt[(kc*8 + i)*VSTR + r] = z;
    }
  }
  __syncthreads();

  const int g = lane >> 4;
  const int q4 = lane & 15;

  for (int chunk = wid; chunk < 13; chunk += 4) {
    const int q0 = chunk*16;
    int qr = q0 + q4;
    qr = (qr < 197) ? qr : 196;
    bf16x8 qa[2];
    #pragma unroll
    for (int kk=0;kk<2;++kk)
      qa[kk] = *(const bf16x8*)(QKV + (rowbase + qr)*N_QKV + h*64 + kk*32 + g*8);
    f32x4 zf = {0.f,0.f,0.f,0.f};
    f32x4 s[13];
    #pragma unroll
    for (int nf=0;nf<13;++nf) s[nf] = zf;
    #pragma unroll
    for (int nf=0;nf<13;++nf) {
      #pragma unroll
      for (int kk=0;kk<2;++kk) {
        bf16x8 kb = *(const bf16x8*)(Kl + (nf*16 + q4)*KSTR + kk*32 + g*8);
        s[nf] = __builtin_amdgcn_mfma_f32_16x16x32_bf16(kb, qa[kk], s[nf], 0, 0, 0);
      }
    }
    float m = -1e30f;
    #pragma unroll
    for (int nf=0;nf<13;++nf) {
      #pragma unroll
      for (int j=0;j<4;++j) {
        const int kg = nf*16 + g*4 + j;
        float v = s[nf][j]*0.125f;
        v = (kg < 197) ? v : -1e30f;
        s[nf][j] = v;
        m = fmaxf(m, v);
      }
    }
    m = fmaxf(m, __shfl_xor(m, 16));
    m = fmaxf(m, __shfl_xor(m, 32));
    float lsum = 0.f;
    #pragma unroll
    for (int nf=0;nf<13;++nf) {
      #pragma unroll
      for (int j=0;j<4;++j) {
        float p = __expf(s[nf][j] - m);
        s[nf][j] = p;
        lsum += p;
      }
    }
    lsum += __shfl_xor(lsum, 16);
    lsum += __shfl_xor(lsum, 32);
    bf16x4 pa[13];
    #pragma unroll
    for (int nf=0;nf<13;++nf) {
      int2v pr;
      pr[0] = pack2bf(s[nf][0], s[nf][1]);
      pr[1] = pack2bf(s[nf][2], s[nf][3]);
      pa[nf] = *(bf16x4*)&pr;
    }
    f32x4 o[4] = {};
    #pragma unroll
    for (int nf=0; nf<13; ++nf) {
      #pragma unroll
      for (int df=0; df<4; ++df) {
        bf16x4 vb = *(const bf16x4*)(Vt + (df*16 + q4)*VSTR + nf*16 + g*4);
        o[df] = mfma16(pa[nf], vb, o[df]);
      }
    }
    // coalesced O epilogue: stage 16x64 tile in LDS, write 128B dense rows
    float ldiv[4];
    #pragma unroll
    for (int j=0;j<4;++j) ldiv[j] = __shfl(lsum, g*4 + j);
    asm volatile("s_waitcnt lgkmcnt(0)" ::: "memory"); SB0();
    #pragma unroll
    for (int df=0; df<4; ++df)
      #pragma unroll
      for (int j=0;j<4;++j)
        Ol[wid][(g*4 + j)*OSTR + df*16 + q4] = (BF16)(o[df][j] / ldiv[j]);
    asm volatile("s_waitcnt lgkmcnt(0)" ::: "memory"); SB0();
    #pragma unroll
    for (int it=0; it<2; ++it) {
      const int lr = (lane >> 3) + it*8;
      const int chk = lane & 7;
      const int r = q0 + lr;
      int4v v = *(const int4v*)(&Ol[wid][lr*OSTR + chk*8]);
      if (r < 197)
        *(int4v*)(O + (rowbase + r)*768 + h*64 + chk*8) = v;
    }
  }
}

// ---------------- host launcher ----------------
extern "C" void kernel_launch(void* const* d_in, const int* in_sizes, int n_in,
                              void* d_out, int out_size, void* d_ws, size_t ws_size,
                              hipStream_t stream) {
  const float* tokens = (const float*)d_in[0];
  const float* qkv_w  = (const float*)d_in[1];
  const float* qkv_b  = (const float*)d_in[2];
  const float* proj_w = (const float*)d_in[3];
  const float* proj_b = (const float*)d_in[4];
  const float* gate_w = (const float*)d_in[5];
  const float* lora_a = (const float*)d_in[6];
  const float* lora_b = (const float*)d_in[7];

  size_t off = 0;
  auto take = [&](size_t bytes) {
    off = (off + 255) & ~(size_t)255;
    void* p = (char*)d_ws + off;
    off += bytes;
    return p;
  };
  BF16* Waug  = (BF16*)take((size_t)N_QKV*KAUG*2);
  BF16* Pb    = (BF16*)take((size_t)D_IN*D_IN*2);
  BF16* LAt   = (BF16*)take((size_t)64*D_IN*2);
  BF16* Aaug  = (BF16*)take((size_t)MTOK*KAUG*2);
  float* gates= (float*)take((size_t)MTOK*8*4);
  BF16* QKVb  = (BF16*)take((size_t)MTOK*N_QKV*2);
  BF16* Oc    = (BF16*)take((size_t)MTOK*D_IN*2);

  prep_waug_k<<<(N_QKV*KAUG + 255)/256, 256, 0, stream>>>(qkv_w, lora_b, Waug);
  prep_pb_k<<<(D_IN*D_IN + 255)/256, 256, 0, stream>>>(proj_w, Pb);
  prep_lat_k<<<(64*D_IN + 255)/256, 256, 0, stream>>>(lora_a, LAt);
  token_prep_k<<<MTOK/4, 256, 0, stream>>>(tokens, gate_w, Aaug, gates);
  gemm_bt_k<64,64,0><<<dim3(1, MTOK/64), 256, 0, stream>>>(
      Aaug, KAUG, LAt, D_IN, gates, (void*)(Aaug + 768), KAUG, MTOK, D_IN);
  // augmented QKV GEMM: A-LDS/B-L2, 3 blocks/CU (99 x 18 blocks)
  gemm3_k<1, 18, KAUG, KAUG, N_QKV><<<99*18, 256, 0, stream>>>(
      Aaug, Waug, qkv_b, (void*)QKVb, MTOK, KAUG);
  attn_k<<<768, 256, 0, stream>>>(QKVb, Oc);
  // output projection: same structure, single occupancy round (99 x 6)
  gemm3_k<2, 6, D_IN, D_IN, D_IN><<<99*6, 256, 0, stream>>>(
      Oc, Pb, proj_b, d_out, MTOK, D_IN);
}

// Round 13
// 161.162 us; speedup vs baseline: 1.4236x; 1.4236x over previous
//
#include <hip/hip_runtime.h>
#include <hip/hip_bf16.h>

typedef __hip_bfloat16 BF16;
typedef __attribute__((ext_vector_type(8))) short bf16x8;
typedef __attribute__((ext_vector_type(4))) short bf16x4;
typedef __attribute__((ext_vector_type(4))) float f32x4;
typedef __attribute__((ext_vector_type(4))) int int4v;
typedef __attribute__((ext_vector_type(2))) int int2v;

#define MTOK 12608      // 64*197 tokens
#define D_IN 768
#define KAUG 832        // 768 + 64 (E*R)
#define N_QKV 2304

#define AS1 __attribute__((address_space(1)))
#define AS3 __attribute__((address_space(3)))
#define SB0() __builtin_amdgcn_sched_barrier(0)

#if __has_builtin(__builtin_amdgcn_mfma_f32_16x16x16bf16_1k)
__device__ __forceinline__ f32x4 mfma16(bf16x4 a, bf16x4 b, f32x4 c) {
  return __builtin_amdgcn_mfma_f32_16x16x16bf16_1k(a, b, c, 0, 0, 0);
}
#else
__device__ __forceinline__ f32x4 mfma16(bf16x4 a, bf16x4 b, f32x4 c) {
  f32x4 d;
  asm volatile("v_mfma_f32_16x16x16_bf16 %0, %1, %2, %3"
               : "=v"(d) : "v"(a), "v"(b), "0"(c));
  return d;
}
#endif

// ---------------- merged weight-prep kernel (one launch) ----------------
// region 0: Waug [2304][832]  (qkv_w | lora_b^T)   2,916,... -> 1,916,928 elems
// region 1: Pb   [768][768]                          589,824 elems
// region 2: LAt  [64][768]                            49,152 elems
__global__ __launch_bounds__(256) void prep_all_k(const float* __restrict__ qkv_w,
                                                  const float* __restrict__ lora_b,
                                                  const float* __restrict__ proj_w,
                                                  const float* __restrict__ lora_a,
                                                  BF16* __restrict__ Waug,
                                                  BF16* __restrict__ Pb,
                                                  BF16* __restrict__ LAt) {
  int idx = blockIdx.x*256 + threadIdx.x;
  const int N1 = N_QKV*KAUG;              // 1,916,928
  const int N2 = N1 + D_IN*D_IN;          // + 589,824
  const int N3 = N2 + 64*D_IN;            // + 49,152
  if (idx < N1) {
    int k = idx / KAUG, c = idx - k*KAUG;
    float v = (c < D_IN) ? qkv_w[k*D_IN + c] : lora_b[(size_t)(c - D_IN)*N_QKV + k];
    Waug[idx] = (BF16)v;
  } else if (idx < N2) {
    int i = idx - N1;
    Pb[i] = (BF16)proj_w[i];
  } else if (idx < N3) {
    int i = idx - N2;
    int j = i / D_IN, d = i - j*D_IN;
    LAt[i] = (BF16)lora_a[(size_t)(j >> 3)*6144 + d*8 + (j & 7)];
  }
}

// ---------------- token prep: float4-vectorized cast + gate softmax -------
__global__ __launch_bounds__(256) void token_prep_k(const float* __restrict__ tokens,
                                                    const float* __restrict__ gate_w,
                                                    BF16* __restrict__ Aaug,
                                                    float* __restrict__ gates) {
  int w = blockIdx.x*4 + (threadIdx.x >> 6);
  int lane = threadIdx.x & 63;
  if (w >= MTOK) return;
  const float4* x4 = (const float4*)(tokens + (size_t)w*D_IN);
  float4 xv[3];
  #pragma unroll
  for (int i=0;i<3;++i) xv[i] = x4[lane + 64*i];
  #pragma unroll
  for (int i=0;i<3;++i) {
    ushort4 u;
    BF16 b0 = (BF16)xv[i].x, b1 = (BF16)xv[i].y, b2 = (BF16)xv[i].z, b3 = (BF16)xv[i].w;
    u.x = *(unsigned short*)&b0; u.y = *(unsigned short*)&b1;
    u.z = *(unsigned short*)&b2; u.w = *(unsigned short*)&b3;
    *(ushort4*)(Aaug + (size_t)w*KAUG + (lane + 64*i)*4) = u;
  }
  float g[8] = {0,0,0,0,0,0,0,0};
  #pragma unroll
  for (int i=0;i<3;++i) {
    const int d4 = (lane + 64*i)*4;
    #pragma unroll
    for (int e=0;e<8;++e) {
      float4 gw = *(const float4*)(gate_w + e*D_IN + d4);
      g[e] += xv[i].x*gw.x + xv[i].y*gw.y + xv[i].z*gw.z + xv[i].w*gw.w;
    }
  }
  #pragma unroll
  for (int e=0;e<8;++e) {
    #pragma unroll
    for (int off=32; off; off >>= 1) g[e] += __shfl_xor(g[e], off);
  }
  float mx = g[0];
  #pragma unroll
  for (int e=1;e<8;++e) mx = fmaxf(mx, g[e]);
  float pe[8]; float ssum = 0.f;
  #pragma unroll
  for (int e=0;e<8;++e) { pe[e] = __expf(g[e]-mx); ssum += pe[e]; }
  float inv = 1.f/ssum;
  if (lane < 8) {
    float val = 0.f;
    #pragma unroll
    for (int e=0;e<8;++e) val = (lane==e) ? pe[e]*inv : val;
    gates[(size_t)w*8 + lane] = val;
  }
}

// ---------------- small 2-phase GEMM-BT (h-GEMM only) ----------------
template<int ROWS>
__device__ __forceinline__ void stage_bt(const BF16* __restrict__ g, int ldg, int row0, int M,
                                         BF16* lds, int kbase, int t) {
  constexpr int NIT = ROWS*8/256;
  #pragma unroll
  for (int it=0; it<NIT; ++it) {
    int c = it*256 + t;
    int r = c >> 3, kc = c & 7;
    int rg = row0 + r;
    rg = (rg < M) ? rg : (M-1);
    const BF16* gp = g + (size_t)rg*ldg + kbase + kc*8;
    BF16* lp = lds + (it*256 + (t & ~63))*8;
    __builtin_amdgcn_global_load_lds((const AS1 void*)gp, (AS3 void*)lp, 16, 0, 0);
  }
}

template<int BM, int BN, int EPI>
__global__ __launch_bounds__(256,3) void gemm_bt_k(const BF16* __restrict__ A, int lda,
                                                   const BF16* __restrict__ Bt, int ldb,
                                                   const float* __restrict__ aux,
                                                   void* __restrict__ Cv, int ldc,
                                                   int M, int K) {
  constexpr int BK = 64;
  constexpr int WM = BM/2, WN = BN/2;
  constexpr int MF = WM/16, NF = WN/16;
  __shared__ BF16 Al[BM*BK];
  __shared__ BF16 Bl[BN*BK];
  const int n0 = blockIdx.x*BN, m0 = blockIdx.y*BM;
  const int t = threadIdx.x, lane = t & 63, wid = t >> 6;
  const int wm = (wid >> 1)*WM, wn = (wid & 1)*WN;
  f32x4 acc[MF][NF] = {};
  const int KT = K/BK;
  for (int kt=0; kt<KT; ++kt) {
    stage_bt<BM>(A, lda, m0, M, Al, kt*BK, t);
    stage_bt<BN>(Bt, ldb, n0, 1<<30, Bl, kt*BK, t);
    __syncthreads();
    #pragma unroll
    for (int kk=0; kk<2; ++kk) {
      bf16x8 a[MF], b[NF];
      const int col = kk*32 + (lane >> 4)*8;
      #pragma unroll
      for (int m=0;m<MF;++m) a[m] = *(const bf16x8*)(Al + (wm + m*16 + (lane & 15))*BK + col);
      #pragma unroll
      for (int n=0;n<NF;++n) b[n] = *(const bf16x8*)(Bl + (wn + n*16 + (lane & 15))*BK + col);
      #pragma unroll
      for (int m=0;m<MF;++m)
        #pragma unroll
        for (int n=0;n<NF;++n)
          acc[m][n] = __builtin_amdgcn_mfma_f32_16x16x32_bf16(a[m], b[n], acc[m][n], 0, 0, 0);
    }
    __syncthreads();
  }
  #pragma unroll
  for (int m=0;m<MF;++m) {
    #pragma unroll
    for (int n=0;n<NF;++n) {
      const int rb = m0 + wm + m*16 + (lane >> 4)*4;
      const int c = n0 + wn + n*16 + (lane & 15);
      #pragma unroll
      for (int j=0;j<4;++j) {
        const int r = rb + j;
        if (r < M) {
          float v = acc[m][n][j];
          if (EPI == 0) {
            v *= aux[(size_t)r*8 + (c >> 3)];
            ((BF16*)Cv)[(size_t)r*ldc + c] = (BF16)v;
          } else if (EPI == 1) {
            v += aux[c];
            ((BF16*)Cv)[(size_t)r*ldc + c] = (BF16)v;
          } else {
            v += aux[c];
            ((float*)Cv)[(size_t)r*ldc + c] = v;
          }
        }
      }
    }
  }
}

// ---------------- 128x128 2-phase double-buffered GEMM-BT ----------------
// 2 blocks/CU; G4 swizzle; cross-block TLP fills wait stalls (round-6/7).
// Round-12 confirmed this config locally optimal: B-direct-from-L2 (gemm3)
// regressed 2x (B loads on critical path, 16 cachelines/instr L2 latency);
// wave-retile variants all blow LDS>2blk/CU or worsen ds_read/MFMA ratio.
template<int EPI, int NBN, int LDA, int LDB, int LDC>
__global__ __launch_bounds__(256,2) void gemm2_k(const BF16* __restrict__ A,
                                                 const BF16* __restrict__ Bt,
                                                 const float* __restrict__ bias,
                                                 void* __restrict__ Cv,
                                                 int M, int K) {
  __shared__ BF16 Lsh[2][2][8192];          // [buf][A,B][128*64]
  const int t = threadIdx.x, lane = t & 63, wid = t >> 6;
  const int nwg = gridDim.x;
  const int q8 = nwg >> 3, r8 = nwg & 7;
  const int xcd = blockIdx.x & 7, pos = blockIdx.x >> 3;
  const int wg = (xcd < r8 ? xcd*(q8+1) : r8*(q8+1) + (xcd - r8)*q8) + pos;
  const int mb = wg / NBN, nb = wg - mb*NBN;
  const int m0 = mb*128, n0 = nb*128;
  const int KT = K/64;
  const int q4 = lane & 15;
  const int wm = (wid >> 1)*64, wn = (wid & 1)*64;

  const BF16 *sA[4], *sB[4];
  #pragma unroll
  for (int it=0; it<4; ++it) {
    int c = it*256 + t;
    int r = c >> 3, p = c & 7;
    int sc = p ^ (r & 7);
    int ra = m0 + r; ra = ra < M ? ra : M-1;
    sA[it] = A  + (size_t)ra*LDA + sc*8;
    sB[it] = Bt + (size_t)(n0 + r)*LDB + sc*8;
  }
  auto stageAB = [&](int buf, int tile) {
    #pragma unroll
    for (int it=0; it<4; ++it)
      __builtin_amdgcn_global_load_lds((const AS1 void*)(sA[it] + tile*64),
        (AS3 void*)(&Lsh[buf][0][0] + (it*256 + (t & ~63))*8), 16, 0, 0);
    #pragma unroll
    for (int it=0; it<4; ++it)
      __builtin_amdgcn_global_load_lds((const AS1 void*)(sB[it] + tile*64),
        (AS3 void*)(&Lsh[buf][1][0] + (it*256 + (t & ~63))*8), 16, 0, 0);
  };

  const int sw = (q4 & 7) << 3;
  const int ck[2] = { (((lane >> 4)*8)) ^ sw, ((32 + (lane >> 4)*8)) ^ sw };

  f32x4 acc[4][4] = {};
  stageAB(0, 0);
  asm volatile("s_waitcnt vmcnt(0)" ::: "memory"); SB0();
  __builtin_amdgcn_s_barrier();

  for (int kt = 0; kt < KT; ++kt) {
    const int buf = kt & 1;
    if (kt+1 < KT) stageAB(buf^1, kt+1);
    bf16x8 a[4][2], b[4][2];
    #pragma unroll
    for (int m=0;m<4;++m)
      #pragma unroll
      for (int kk=0;kk<2;++kk)
        a[m][kk] = *(const bf16x8*)(&Lsh[buf][0][0] + (wm + m*16 + q4)*64 + ck[kk]);
    #pragma unroll
    for (int n=0;n<4;++n)
      #pragma unroll
      for (int kk=0;kk<2;++kk)
        b[n][kk] = *(const bf16x8*)(&Lsh[buf][1][0] + (wn + n*16 + q4)*64 + ck[kk]);
    asm volatile("s_waitcnt lgkmcnt(0)" ::: "memory"); SB0();
    __builtin_amdgcn_s_setprio(1);
    #pragma unroll
    for (int kk=0;kk<2;++kk)
      #pragma unroll
      for (int m=0;m<4;++m)
        #pragma unroll
        for (int n=0;n<4;++n)
          acc[m][n] = __builtin_amdgcn_mfma_f32_16x16x32_bf16(a[m][kk], b[n][kk], acc[m][n], 0,0,0);
    __builtin_amdgcn_s_setprio(0);
    SB0();
    if (kt+1 < KT) asm volatile("s_waitcnt vmcnt(0)" ::: "memory");
    SB0();
    __builtin_amdgcn_s_barrier();
  }

  float bv[4];
  #pragma unroll
  for (int n=0;n<4;++n) bv[n] = bias[n0 + wn + n*16 + q4];
  #pragma unroll
  for (int m=0;m<4;++m) {
    #pragma unroll
    for (int j=0;j<4;++j) {
      const int r = m0 + wm + m*16 + (lane >> 4)*4 + j;
      if (r < M) {
        #pragma unroll
        for (int n=0;n<4;++n) {
          float v = acc[m][n][j] + bv[n];
          const size_t idx = (size_t)r*LDC + n0 + wn + n*16 + q4;
          if (EPI == 1) ((BF16*)Cv)[idx] = (BF16)v;
          else          ((float*)Cv)[idx] = v;
        }
      }
    }
  }
}

// ---------------- attention: swapped QK^T + direct-register PV ----------
__device__ __forceinline__ int pack2bf(float lo, float hi) {
  BF16 a = (BF16)lo, b = (BF16)hi;
  unsigned short al = *(unsigned short*)&a, bh = *(unsigned short*)&b;
  return (int)(((unsigned)bh << 16) | (unsigned)al);
}

__global__ __launch_bounds__(256,2) void attn_k(const BF16* __restrict__ QKV,
                                                BF16* __restrict__ O) {
  constexpr int KSTR = 72;   // 144B rows: 2-way bank alias (free)
  constexpr int VSTR = 236;  // 472B rows: 16 lanes cover all 32 banks
  constexpr int OSTR = 72;   // O-stage rows 144B, 16B-aligned, 2-way max
  __shared__ BF16 Kl[208*KSTR];
  __shared__ BF16 Vt[64*VSTR];
  __shared__ BF16 Ol[4][16*OSTR];
  const int bh = blockIdx.x;
  const int b = bh / 12, h = bh - b*12;
  const size_t rowbase = (size_t)b*197;
  const int t = threadIdx.x, lane = t & 63, wid = t >> 6;
  const BF16 z = (BF16)0.0f;
  // ---- prefetch-split staging: issue ALL global loads, then store ----
  int4v rk[7], rv[7];
  int cc[7];
  #pragma unroll
  for (int it=0; it<7; ++it) {
    int c = t + it*256; c = (c < 1663) ? c : 1663;
    cc[it] = c;
    int r = c >> 3, kc = c & 7;
    int rr = (r < 197) ? r : 196;
    rk[it] = *(const int4v*)(QKV + (rowbase + rr)*N_QKV + 768  + h*64 + kc*8);
    rv[it] = *(const int4v*)(QKV + (rowbase + rr)*N_QKV + 1536 + h*64 + kc*8);
  }
  #pragma unroll
  for (int it=0; it<7; ++it) {
    int c = cc[it];
    int r = c >> 3, kc = c & 7;
    int4v kval = rk[it];
    if (r >= 197) { kval[0]=0; kval[1]=0; kval[2]=0; kval[3]=0; }
    *(int4v*)(Kl + r*KSTR + kc*8) = kval;
    const BF16* pv = (const BF16*)&rv[it];
    if (r < 197) {
      #pragma unroll
      for (int i=0;i<8;++i) Vt[(kc*8 + i)*VSTR + r] = pv[i];
    } else {
      #pragma unroll
      for (int i=0;i<8;++i) Vt[(kc*8 + i)*VSTR + r] = z;
    }
  }
  __syncthreads();

  const int g = lane >> 4;
  const int q4 = lane & 15;

  for (int chunk = wid; chunk < 13; chunk += 4) {
    const int q0 = chunk*16;
    int qr = q0 + q4;
    qr = (qr < 197) ? qr : 196;
    bf16x8 qa[2];
    #pragma unroll
    for (int kk=0;kk<2;++kk)
      qa[kk] = *(const bf16x8*)(QKV + (rowbase + qr)*N_QKV + h*64 + kk*32 + g*8);
    f32x4 zf = {0.f,0.f,0.f,0.f};
    f32x4 s[13];
    #pragma unroll
    for (int nf=0;nf<13;++nf) s[nf] = zf;
    #pragma unroll
    for (int nf=0;nf<13;++nf) {
      #pragma unroll
      for (int kk=0;kk<2;++kk) {
        bf16x8 kb = *(const bf16x8*)(Kl + (nf*16 + q4)*KSTR + kk*32 + g*8);
        s[nf] = __builtin_amdgcn_mfma_f32_16x16x32_bf16(kb, qa[kk], s[nf], 0, 0, 0);
      }
    }
    float m = -1e30f;
    #pragma unroll
    for (int nf=0;nf<13;++nf) {
      #pragma unroll
      for (int j=0;j<4;++j) {
        const int kg = nf*16 + g*4 + j;
        float v = s[nf][j]*0.125f;
        v = (kg < 197) ? v : -1e30f;
        s[nf][j] = v;
        m = fmaxf(m, v);
      }
    }
    m = fmaxf(m, __shfl_xor(m, 16));
    m = fmaxf(m, __shfl_xor(m, 32));
    float lsum = 0.f;
    #pragma unroll
    for (int nf=0;nf<13;++nf) {
      #pragma unroll
      for (int j=0;j<4;++j) {
        float p = __expf(s[nf][j] - m);
        s[nf][j] = p;
        lsum += p;
      }
    }
    lsum += __shfl_xor(lsum, 16);
    lsum += __shfl_xor(lsum, 32);
    bf16x4 pa[13];
    #pragma unroll
    for (int nf=0;nf<13;++nf) {
      int2v pr;
      pr[0] = pack2bf(s[nf][0], s[nf][1]);
      pr[1] = pack2bf(s[nf][2], s[nf][3]);
      pa[nf] = *(bf16x4*)&pr;
    }
    f32x4 o[4] = {};
    #pragma unroll
    for (int nf=0; nf<13; ++nf) {
      #pragma unroll
      for (int df=0; df<4; ++df) {
        bf16x4 vb = *(const bf16x4*)(Vt + (df*16 + q4)*VSTR + nf*16 + g*4);
        o[df] = mfma16(pa[nf], vb, o[df]);
      }
    }
    // coalesced O epilogue: stage 16x64 tile in LDS, write 128B dense rows
    float ldiv[4];
    #pragma unroll
    for (int j=0;j<4;++j) ldiv[j] = __shfl(lsum, g*4 + j);
    asm volatile("s_waitcnt lgkmcnt(0)" ::: "memory"); SB0();
    #pragma unroll
    for (int df=0; df<4; ++df)
      #pragma unroll
      for (int j=0;j<4;++j)
        Ol[wid][(g*4 + j)*OSTR + df*16 + q4] = (BF16)(o[df][j] / ldiv[j]);
    asm volatile("s_waitcnt lgkmcnt(0)" ::: "memory"); SB0();
    #pragma unroll
    for (int it=0; it<2; ++it) {
      const int lr = (lane >> 3) + it*8;
      const int chk = lane & 7;
      const int r = q0 + lr;
      int4v v = *(const int4v*)(&Ol[wid][lr*OSTR + chk*8]);
      if (r < 197)
        *(int4v*)(O + (rowbase + r)*768 + h*64 + chk*8) = v;
    }
  }
}

// ---------------- host launcher ----------------
extern "C" void kernel_launch(void* const* d_in, const int* in_sizes, int n_in,
                              void* d_out, int out_size, void* d_ws, size_t ws_size,
                              hipStream_t stream) {
  const float* tokens = (const float*)d_in[0];
  const float* qkv_w  = (const float*)d_in[1];
  const float* qkv_b  = (const float*)d_in[2];
  const float* proj_w = (const float*)d_in[3];
  const float* proj_b = (const float*)d_in[4];
  const float* gate_w = (const float*)d_in[5];
  const float* lora_a = (const float*)d_in[6];
  const float* lora_b = (const float*)d_in[7];

  size_t off = 0;
  auto take = [&](size_t bytes) {
    off = (off + 255) & ~(size_t)255;
    void* p = (char*)d_ws + off;
    off += bytes;
    return p;
  };
  BF16* Waug  = (BF16*)take((size_t)N_QKV*KAUG*2);
  BF16* Pb    = (BF16*)take((size_t)D_IN*D_IN*2);
  BF16* LAt   = (BF16*)take((size_t)64*D_IN*2);
  BF16* Aaug  = (BF16*)take((size_t)MTOK*KAUG*2);
  float* gates= (float*)take((size_t)MTOK*8*4);
  BF16* QKVb  = (BF16*)take((size_t)MTOK*N_QKV*2);
  BF16* Oc    = (BF16*)take((size_t)MTOK*D_IN*2);

  const int NPREP = N_QKV*KAUG + D_IN*D_IN + 64*D_IN;
  prep_all_k<<<(NPREP + 255)/256, 256, 0, stream>>>(
      qkv_w, lora_b, proj_w, lora_a, Waug, Pb, LAt);
  token_prep_k<<<MTOK/4, 256, 0, stream>>>(tokens, gate_w, Aaug, gates);
  gemm_bt_k<64,64,0><<<dim3(1, MTOK/64), 256, 0, stream>>>(
      Aaug, KAUG, LAt, D_IN, gates, (void*)(Aaug + 768), KAUG, MTOK, D_IN);
  // augmented QKV GEMM: 128^2 dbuf 2-phase, 2 blocks/CU (99 x 18 blocks)
  gemm2_k<1, 18, KAUG, KAUG, N_QKV><<<99*18, 256, 0, stream>>>(
      Aaug, Waug, qkv_b, (void*)QKVb, MTOK, KAUG);
  attn_k<<<768, 256, 0, stream>>>(QKVb, Oc);
  // output projection: same structure (99 x 6 blocks)
  gemm2_k<2, 6, D_IN, D_IN, D_IN><<<99*6, 256, 0, stream>>>(
      Oc, Pb, proj_b, d_out, MTOK, D_IN);
}

// Round 14
// 152.563 us; speedup vs baseline: 1.5038x; 1.0564x over previous
//
#include <hip/hip_runtime.h>
#include <hip/hip_bf16.h>

typedef __hip_bfloat16 BF16;
typedef __attribute__((ext_vector_type(8))) short bf16x8;
typedef __attribute__((ext_vector_type(4))) short bf16x4;
typedef __attribute__((ext_vector_type(4))) float f32x4;
typedef __attribute__((ext_vector_type(4))) int int4v;
typedef __attribute__((ext_vector_type(2))) int int2v;

#define MTOK 12608      // 64*197 tokens
#define D_IN 768
#define KAUG 832        // 768 + 64 (E*R)
#define N_QKV 2304

#define AS1 __attribute__((address_space(1)))
#define AS3 __attribute__((address_space(3)))
#define SB0() __builtin_amdgcn_sched_barrier(0)

#if __has_builtin(__builtin_amdgcn_mfma_f32_16x16x16bf16_1k)
__device__ __forceinline__ f32x4 mfma16(bf16x4 a, bf16x4 b, f32x4 c) {
  return __builtin_amdgcn_mfma_f32_16x16x16bf16_1k(a, b, c, 0, 0, 0);
}
#else
__device__ __forceinline__ f32x4 mfma16(bf16x4 a, bf16x4 b, f32x4 c) {
  f32x4 d;
  asm volatile("v_mfma_f32_16x16x16_bf16 %0, %1, %2, %3"
               : "=v"(d) : "v"(a), "v"(b), "0"(c));
  return d;
}
#endif

// ------- merged prep: weight casts + token cast/gates in ONE launch -------
#define NPREP (N_QKV*KAUG + D_IN*D_IN + 64*D_IN)
#define PREP_BLK ((NPREP + 255)/256)        // 9984
#define TOK_BLK (MTOK/4)                    // 3152

__global__ __launch_bounds__(256) void prep_tok_k(const float* __restrict__ qkv_w,
                                                  const float* __restrict__ lora_b,
                                                  const float* __restrict__ proj_w,
                                                  const float* __restrict__ lora_a,
                                                  const float* __restrict__ tokens,
                                                  const float* __restrict__ gate_w,
                                                  BF16* __restrict__ Waug,
                                                  BF16* __restrict__ Pb,
                                                  BF16* __restrict__ LAt,
                                                  BF16* __restrict__ Aaug,
                                                  float* __restrict__ gates) {
  if (blockIdx.x < PREP_BLK) {
    int idx = blockIdx.x*256 + threadIdx.x;
    const int N1 = N_QKV*KAUG;
    const int N2 = N1 + D_IN*D_IN;
    const int N3 = N2 + 64*D_IN;
    if (idx < N1) {
      int k = idx / KAUG, c = idx - k*KAUG;
      float v = (c < D_IN) ? qkv_w[k*D_IN + c] : lora_b[(size_t)(c - D_IN)*N_QKV + k];
      Waug[idx] = (BF16)v;
    } else if (idx < N2) {
      int i = idx - N1;
      Pb[i] = (BF16)proj_w[i];
    } else if (idx < N3) {
      int i = idx - N2;
      int j = i / D_IN, d = i - j*D_IN;
      LAt[i] = (BF16)lora_a[(size_t)(j >> 3)*6144 + d*8 + (j & 7)];
    }
    return;
  }
  // ---- token path ----
  int w = (blockIdx.x - PREP_BLK)*4 + (threadIdx.x >> 6);
  int lane = threadIdx.x & 63;
  if (w >= MTOK) return;
  const float4* x4 = (const float4*)(tokens + (size_t)w*D_IN);
  float4 xv[3];
  #pragma unroll
  for (int i=0;i<3;++i) xv[i] = x4[lane + 64*i];
  #pragma unroll
  for (int i=0;i<3;++i) {
    ushort4 u;
    BF16 b0 = (BF16)xv[i].x, b1 = (BF16)xv[i].y, b2 = (BF16)xv[i].z, b3 = (BF16)xv[i].w;
    u.x = *(unsigned short*)&b0; u.y = *(unsigned short*)&b1;
    u.z = *(unsigned short*)&b2; u.w = *(unsigned short*)&b3;
    *(ushort4*)(Aaug + (size_t)w*KAUG + (lane + 64*i)*4) = u;
  }
  float g[8] = {0,0,0,0,0,0,0,0};
  #pragma unroll
  for (int i=0;i<3;++i) {
    const int d4 = (lane + 64*i)*4;
    #pragma unroll
    for (int e=0;e<8;++e) {
      float4 gw = *(const float4*)(gate_w + e*D_IN + d4);
      g[e] += xv[i].x*gw.x + xv[i].y*gw.y + xv[i].z*gw.z + xv[i].w*gw.w;
    }
  }
  #pragma unroll
  for (int e=0;e<8;++e) {
    #pragma unroll
    for (int off=32; off; off >>= 1) g[e] += __shfl_xor(g[e], off);
  }
  float mx = g[0];
  #pragma unroll
  for (int e=1;e<8;++e) mx = fmaxf(mx, g[e]);
  float pe[8]; float ssum = 0.f;
  #pragma unroll
  for (int e=0;e<8;++e) { pe[e] = __expf(g[e]-mx); ssum += pe[e]; }
  float inv = 1.f/ssum;
  if (lane < 8) {
    float val = 0.f;
    #pragma unroll
    for (int e=0;e<8;++e) val = (lane==e) ? pe[e]*inv : val;
    gates[(size_t)w*8 + lane] = val;
  }
}

// ---------------- small 2-phase GEMM-BT (h-GEMM only) ----------------
template<int ROWS>
__device__ __forceinline__ void stage_bt(const BF16* __restrict__ g, int ldg, int row0, int M,
                                         BF16* lds, int kbase, int t) {
  constexpr int NIT = ROWS*8/256;
  #pragma unroll
  for (int it=0; it<NIT; ++it) {
    int c = it*256 + t;
    int r = c >> 3, kc = c & 7;
    int rg = row0 + r;
    rg = (rg < M) ? rg : (M-1);
    const BF16* gp = g + (size_t)rg*ldg + kbase + kc*8;
    BF16* lp = lds + (it*256 + (t & ~63))*8;
    __builtin_amdgcn_global_load_lds((const AS1 void*)gp, (AS3 void*)lp, 16, 0, 0);
  }
}

template<int BM, int BN, int EPI>
__global__ __launch_bounds__(256,3) void gemm_bt_k(const BF16* __restrict__ A, int lda,
                                                   const BF16* __restrict__ Bt, int ldb,
                                                   const float* __restrict__ aux,
                                                   void* __restrict__ Cv, int ldc,
                                                   int M, int K) {
  constexpr int BK = 64;
  constexpr int WM = BM/2, WN = BN/2;
  constexpr int MF = WM/16, NF = WN/16;
  __shared__ BF16 Al[BM*BK];
  __shared__ BF16 Bl[BN*BK];
  const int n0 = blockIdx.x*BN, m0 = blockIdx.y*BM;
  const int t = threadIdx.x, lane = t & 63, wid = t >> 6;
  const int wm = (wid >> 1)*WM, wn = (wid & 1)*WN;
  f32x4 acc[MF][NF] = {};
  const int KT = K/BK;
  for (int kt=0; kt<KT; ++kt) {
    stage_bt<BM>(A, lda, m0, M, Al, kt*BK, t);
    stage_bt<BN>(Bt, ldb, n0, 1<<30, Bl, kt*BK, t);
    __syncthreads();
    #pragma unroll
    for (int kk=0; kk<2; ++kk) {
      bf16x8 a[MF], b[NF];
      const int col = kk*32 + (lane >> 4)*8;
      #pragma unroll
      for (int m=0;m<MF;++m) a[m] = *(const bf16x8*)(Al + (wm + m*16 + (lane & 15))*BK + col);
      #pragma unroll
      for (int n=0;n<NF;++n) b[n] = *(const bf16x8*)(Bl + (wn + n*16 + (lane & 15))*BK + col);
      #pragma unroll
      for (int m=0;m<MF;++m)
        #pragma unroll
        for (int n=0;n<NF;++n)
          acc[m][n] = __builtin_amdgcn_mfma_f32_16x16x32_bf16(a[m], b[n], acc[m][n], 0, 0, 0);
    }
    __syncthreads();
  }
  #pragma unroll
  for (int m=0;m<MF;++m) {
    #pragma unroll
    for (int n=0;n<NF;++n) {
      const int rb = m0 + wm + m*16 + (lane >> 4)*4;
      const int c = n0 + wn + n*16 + (lane & 15);
      #pragma unroll
      for (int j=0;j<4;++j) {
        const int r = rb + j;
        if (r < M) {
          float v = acc[m][n][j];
          if (EPI == 0) {
            v *= aux[(size_t)r*8 + (c >> 3)];
            ((BF16*)Cv)[(size_t)r*ldc + c] = (BF16)v;
          } else if (EPI == 1) {
            v += aux[c];
            ((BF16*)Cv)[(size_t)r*ldc + c] = (BF16)v;
          } else {
            v += aux[c];
            ((float*)Cv)[(size_t)r*ldc + c] = v;
          }
        }
      }
    }
  }
}

// ---------------- BMx128 2-phase double-buffered GEMM-BT ----------------
// Round-14: BM=160 reshapes grids to fix occupancy-round quantization:
// QKV 79x18=1422 -> 3 rounds (was 1782 -> 4); proj 79x6=474 -> 1 round
// (was 594 -> 2). LDS (160+128)*64*2*2 = 73.7KB <= 80KB keeps 2 blk/CU.
template<int BM, int EPI, int NBN, int LDA, int LDB, int LDC>
__global__ __launch_bounds__(256,2) void gemm2_k(const BF16* __restrict__ A,
                                                 const BF16* __restrict__ Bt,
                                                 const float* __restrict__ bias,
                                                 void* __restrict__ Cv,
                                                 int M, int K) {
  constexpr int MF = BM/32;                 // wave M-frags (WM = BM/2)
  constexpr int NITA = BM/32;               // A stage chunks/thread
  __shared__ BF16 LA[2][BM*64];
  __shared__ BF16 LB[2][8192];
  const int t = threadIdx.x, lane = t & 63, wid = t >> 6;
  const int nwg = gridDim.x;
  const int q8 = nwg >> 3, r8 = nwg & 7;
  const int xcd = blockIdx.x & 7, pos = blockIdx.x >> 3;
  const int wg = (xcd < r8 ? xcd*(q8+1) : r8*(q8+1) + (xcd - r8)*q8) + pos;
  const int mb = wg / NBN, nb = wg - mb*NBN;
  const int m0 = mb*BM, n0 = nb*128;
  const int KT = K/64;
  const int q4 = lane & 15;
  const int wm = (wid >> 1)*(BM/2), wn = (wid & 1)*64;

  const BF16 *sA[NITA], *sB[4];
  #pragma unroll
  for (int it=0; it<NITA; ++it) {
    int c = it*256 + t;
    int r = c >> 3, p = c & 7;
    int sc = p ^ (r & 7);
    int ra = m0 + r; ra = ra < M ? ra : M-1;
    sA[it] = A + (size_t)ra*LDA + sc*8;
  }
  #pragma unroll
  for (int it=0; it<4; ++it) {
    int c = it*256 + t;
    int r = c >> 3, p = c & 7;
    int sc = p ^ (r & 7);
    sB[it] = Bt + (size_t)(n0 + r)*LDB + sc*8;
  }
  auto stageAB = [&](int buf, int tile) {
    #pragma unroll
    for (int it=0; it<NITA; ++it)
      __builtin_amdgcn_global_load_lds((const AS1 void*)(sA[it] + tile*64),
        (AS3 void*)(&LA[buf][0] + (it*256 + (t & ~63))*8), 16, 0, 0);
    #pragma unroll
    for (int it=0; it<4; ++it)
      __builtin_amdgcn_global_load_lds((const AS1 void*)(sB[it] + tile*64),
        (AS3 void*)(&LB[buf][0] + (it*256 + (t & ~63))*8), 16, 0, 0);
  };

  const int sw = (q4 & 7) << 3;
  const int ck[2] = { (((lane >> 4)*8)) ^ sw, ((32 + (lane >> 4)*8)) ^ sw };

  f32x4 acc[MF][4] = {};
  stageAB(0, 0);
  asm volatile("s_waitcnt vmcnt(0)" ::: "memory"); SB0();
  __builtin_amdgcn_s_barrier();

  for (int kt = 0; kt < KT; ++kt) {
    const int buf = kt & 1;
    if (kt+1 < KT) stageAB(buf^1, kt+1);
    bf16x8 a[MF][2], b[4][2];
    #pragma unroll
    for (int m=0;m<MF;++m)
      #pragma unroll
      for (int kk=0;kk<2;++kk)
        a[m][kk] = *(const bf16x8*)(&LA[buf][0] + (wm + m*16 + q4)*64 + ck[kk]);
    #pragma unroll
    for (int n=0;n<4;++n)
      #pragma unroll
      for (int kk=0;kk<2;++kk)
        b[n][kk] = *(const bf16x8*)(&LB[buf][0] + (wn + n*16 + q4)*64 + ck[kk]);
    asm volatile("s_waitcnt lgkmcnt(0)" ::: "memory"); SB0();
    __builtin_amdgcn_s_setprio(1);
    #pragma unroll
    for (int kk=0;kk<2;++kk)
      #pragma unroll
      for (int m=0;m<MF;++m)
        #pragma unroll
        for (int n=0;n<4;++n)
          acc[m][n] = __builtin_amdgcn_mfma_f32_16x16x32_bf16(a[m][kk], b[n][kk], acc[m][n], 0,0,0);
    __builtin_amdgcn_s_setprio(0);
    SB0();
    if (kt+1 < KT) asm volatile("s_waitcnt vmcnt(0)" ::: "memory");
    SB0();
    __builtin_amdgcn_s_barrier();
  }

  float bv[4];
  #pragma unroll
  for (int n=0;n<4;++n) bv[n] = bias[n0 + wn + n*16 + q4];
  #pragma unroll
  for (int m=0;m<MF;++m) {
    #pragma unroll
    for (int j=0;j<4;++j) {
      const int r = m0 + wm + m*16 + (lane >> 4)*4 + j;
      if (r < M) {
        #pragma unroll
        for (int n=0;n<4;++n) {
          float v = acc[m][n][j] + bv[n];
          const size_t idx = (size_t)r*LDC + n0 + wn + n*16 + q4;
          if (EPI == 1) ((BF16*)Cv)[idx] = (BF16)v;
          else          ((float*)Cv)[idx] = v;
        }
      }
    }
  }
}

// ---------------- attention: swapped QK^T + direct-register PV ----------
__device__ __forceinline__ int pack2bf(float lo, float hi) {
  BF16 a = (BF16)lo, b = (BF16)hi;
  unsigned short al = *(unsigned short*)&a, bh = *(unsigned short*)&b;
  return (int)(((unsigned)bh << 16) | (unsigned)al);
}

__global__ __launch_bounds__(256,2) void attn_k(const BF16* __restrict__ QKV,
                                                BF16* __restrict__ O) {
  constexpr int KSTR = 72;   // 144B rows: 2-way bank alias (free)
  constexpr int VSTR = 236;  // 472B rows: 16 lanes cover all 32 banks
  constexpr int OSTR = 72;   // O-stage rows 144B, 16B-aligned, 2-way max
  __shared__ BF16 Kl[208*KSTR];
  __shared__ BF16 Vt[64*VSTR];
  __shared__ BF16 Ol[4][16*OSTR];
  const int bh = blockIdx.x;
  const int b = bh / 12, h = bh - b*12;
  const size_t rowbase = (size_t)b*197;
  const int t = threadIdx.x, lane = t & 63, wid = t >> 6;
  const BF16 z = (BF16)0.0f;
  int4v rk[7], rv[7];
  int cc[7];
  #pragma unroll
  for (int it=0; it<7; ++it) {
    int c = t + it*256; c = (c < 1663) ? c : 1663;
    cc[it] = c;
    int r = c >> 3, kc = c & 7;
    int rr = (r < 197) ? r : 196;
    rk[it] = *(const int4v*)(QKV + (rowbase + rr)*N_QKV + 768  + h*64 + kc*8);
    rv[it] = *(const int4v*)(QKV + (rowbase + rr)*N_QKV + 1536 + h*64 + kc*8);
  }
  #pragma unroll
  for (int it=0; it<7; ++it) {
    int c = cc[it];
    int r = c >> 3, kc = c & 7;
    int4v kval = rk[it];
    if (r >= 197) { kval[0]=0; kval[1]=0; kval[2]=0; kval[3]=0; }
    *(int4v*)(Kl + r*KSTR + kc*8) = kval;
    const BF16* pv = (const BF16*)&rv[it];
    if (r < 197) {
      #pragma unroll
      for (int i=0;i<8;++i) Vt[(kc*8 + i)*VSTR + r] = pv[i];
    } else {
      #pragma unroll
      for (int i=0;i<8;++i) Vt[(kc*8 + i)*VSTR + r] = z;
    }
  }
  __syncthreads();

  const int g = lane >> 4;
  const int q4 = lane & 15;

  for (int chunk = wid; chunk < 13; chunk += 4) {
    const int q0 = chunk*16;
    int qr = q0 + q4;
    qr = (qr < 197) ? qr : 196;
    bf16x8 qa[2];
    #pragma unroll
    for (int kk=0;kk<2;++kk)
      qa[kk] = *(const bf16x8*)(QKV + (rowbase + qr)*N_QKV + h*64 + kk*32 + g*8);
    f32x4 zf = {0.f,0.f,0.f,0.f};
    f32x4 s[13];
    #pragma unroll
    for (int nf=0;nf<13;++nf) s[nf] = zf;
    #pragma unroll
    for (int nf=0;nf<13;++nf) {
      #pragma unroll
      for (int kk=0;kk<2;++kk) {
        bf16x8 kb = *(const bf16x8*)(Kl + (nf*16 + q4)*KSTR + kk*32 + g*8);
        s[nf] = __builtin_amdgcn_mfma_f32_16x16x32_bf16(kb, qa[kk], s[nf], 0, 0, 0);
      }
    }
    float m = -1e30f;
    #pragma unroll
    for (int nf=0;nf<13;++nf) {
      #pragma unroll
      for (int j=0;j<4;++j) {
        const int kg = nf*16 + g*4 + j;
        float v = s[nf][j]*0.125f;
        v = (kg < 197) ? v : -1e30f;
        s[nf][j] = v;
        m = fmaxf(m, v);
      }
    }
    m = fmaxf(m, __shfl_xor(m, 16));
    m = fmaxf(m, __shfl_xor(m, 32));
    float lsum = 0.f;
    #pragma unroll
    for (int nf=0;nf<13;++nf) {
      #pragma unroll
      for (int j=0;j<4;++j) {
        float p = __expf(s[nf][j] - m);
        s[nf][j] = p;
        lsum += p;
      }
    }
    lsum += __shfl_xor(lsum, 16);
    lsum += __shfl_xor(lsum, 32);
    bf16x4 pa[13];
    #pragma unroll
    for (int nf=0;nf<13;++nf) {
      int2v pr;
      pr[0] = pack2bf(s[nf][0], s[nf][1]);
      pr[1] = pack2bf(s[nf][2], s[nf][3]);
      pa[nf] = *(bf16x4*)&pr;
    }
    f32x4 o[4] = {};
    #pragma unroll
    for (int nf=0; nf<13; ++nf) {
      #pragma unroll
      for (int df=0; df<4; ++df) {
        bf16x4 vb = *(const bf16x4*)(Vt + (df*16 + q4)*VSTR + nf*16 + g*4);
        o[df] = mfma16(pa[nf], vb, o[df]);
      }
    }
    float ldiv[4];
    #pragma unroll
    for (int j=0;j<4;++j) ldiv[j] = __shfl(lsum, g*4 + j);
    asm volatile("s_waitcnt lgkmcnt(0)" ::: "memory"); SB0();
    #pragma unroll
    for (int df=0; df<4; ++df)
      #pragma unroll
      for (int j=0;j<4;++j)
        Ol[wid][(g*4 + j)*OSTR + df*16 + q4] = (BF16)(o[df][j] / ldiv[j]);
    asm volatile("s_waitcnt lgkmcnt(0)" ::: "memory"); SB0();
    #pragma unroll
    for (int it=0; it<2; ++it) {
      const int lr = (lane >> 3) + it*8;
      const int chk = lane & 7;
      const int r = q0 + lr;
      int4v v = *(const int4v*)(&Ol[wid][lr*OSTR + chk*8]);
      if (r < 197)
        *(int4v*)(O + (rowbase + r)*768 + h*64 + chk*8) = v;
    }
  }
}

// ---------------- host launcher ----------------
extern "C" void kernel_launch(void* const* d_in, const int* in_sizes, int n_in,
                              void* d_out, int out_size, void* d_ws, size_t ws_size,
                              hipStream_t stream) {
  const float* tokens = (const float*)d_in[0];
  const float* qkv_w  = (const float*)d_in[1];
  const float* qkv_b  = (const float*)d_in[2];
  const float* proj_w = (const float*)d_in[3];
  const float* proj_b = (const float*)d_in[4];
  const float* gate_w = (const float*)d_in[5];
  const float* lora_a = (const float*)d_in[6];
  const float* lora_b = (const float*)d_in[7];

  size_t off = 0;
  auto take = [&](size_t bytes) {
    off = (off + 255) & ~(size_t)255;
    void* p = (char*)d_ws + off;
    off += bytes;
    return p;
  };
  BF16* Waug  = (BF16*)take((size_t)N_QKV*KAUG*2);
  BF16* Pb    = (BF16*)take((size_t)D_IN*D_IN*2);
  BF16* LAt   = (BF16*)take((size_t)64*D_IN*2);
  BF16* Aaug  = (BF16*)take((size_t)MTOK*KAUG*2);
  float* gates= (float*)take((size_t)MTOK*8*4);
  BF16* QKVb  = (BF16*)take((size_t)MTOK*N_QKV*2);
  BF16* Oc    = (BF16*)take((size_t)MTOK*D_IN*2);

  // merged weight-prep + token-prep (independent work, one launch)
  prep_tok_k<<<PREP_BLK + TOK_BLK, 256, 0, stream>>>(
      qkv_w, lora_b, proj_w, lora_a, tokens, gate_w,
      Waug, Pb, LAt, Aaug, gates);
  gemm_bt_k<64,64,0><<<dim3(1, MTOK/64), 256, 0, stream>>>(
      Aaug, KAUG, LAt, D_IN, gates, (void*)(Aaug + 768), KAUG, MTOK, D_IN);
  // augmented QKV GEMM: 160x128 dbuf 2-phase, 2 blocks/CU, 79x18 = 1422 (3 rounds)
  gemm2_k<160, 1, 18, KAUG, KAUG, N_QKV><<<79*18, 256, 0, stream>>>(
      Aaug, Waug, qkv_b, (void*)QKVb, MTOK, KAUG);
  attn_k<<<768, 256, 0, stream>>>(QKVb, Oc);
  // output projection: 79x6 = 474 blocks (single occupancy round)
  gemm2_k<160, 2, 6, D_IN, D_IN, D_IN><<<79*6, 256, 0, stream>>>(
      Oc, Pb, proj_b, d_out, MTOK, D_IN);
}